// Round 4
// baseline (226.358 us; speedup 1.0000x reference)
//
#include <hip/hip_runtime.h>
#include <hip/hip_bf16.h>
#include <stdint.h>

#define BATCH 16
#define CIN   256
#define HH    112
#define WW    112
#define GROUPS 2
#define CG    128   // cin per group
#define COG   128   // cout per group
#define CK    32    // cin chunk per K-step group
#define NCHUNK (CG/CK)

typedef __bf16 bf16x8 __attribute__((ext_vector_type(8)));
typedef float  f32x4  __attribute__((ext_vector_type(4)));

// ---- workspace layout ----
#define WB_BYTES   (GROUPS*3*3*COG*CG*2)        // 589824
#define ZBUF_OFF   WB_BYTES
#define ZBUF_BYTES 8192
#define XB_OFF     (ZBUF_OFF + ZBUF_BYTES)      // 598016
#define XB_BYTES   ((size_t)BATCH*HH*WW*CIN*2)  // 102760448
#define WS_NEED    ((size_t)XB_OFF + XB_BYTES)  // 103358464

__device__ inline void load_lds16(const void* g, void* l) {
    __builtin_amdgcn_global_load_lds(
        (const __attribute__((address_space(1))) void*)g,
        (__attribute__((address_space(3))) void*)l, 16, 0, 0);
}

// ---- pre-pass 1: weights OIHW fp32 -> [g][kh][kw][cout][cin] bf16 ----
__global__ __launch_bounds__(256) void k_wcvt(const float* __restrict__ w,
                                              ushort* __restrict__ wb) {
    int i = blockIdx.x * 256 + threadIdx.x;   // 294912 total
    int ci = i & 127;
    int t  = i >> 7;
    int co = t & 127;
    t >>= 7;                                  // t = g*9 + kh*3 + kw
    int kw = t % 3; t /= 3;
    int kh = t % 3;
    int g  = t / 3;
    int src = (((g*COG + co)*CG + ci)*3 + kh)*3 + kw;
    __hip_bfloat16 v = __float2bfloat16(w[src]);
    wb[i] = *reinterpret_cast<ushort*>(&v);
}

// ---- pre-pass 2: x NCHW fp32 -> NHWC bf16 (LDS transpose) ----
#define XPAD 113
__global__ __launch_bounds__(256) void k_xcvt(const float* __restrict__ x,
                                              ushort* __restrict__ xb) {
    __shared__ float tile[64 * XPAD];
    int bid = blockIdx.x;            // 16*112*4 = 7168
    int cc  = bid & 3;               // chunk of 64 channels
    int h   = (bid >> 2) % HH;
    int b   = bid / (4 * HH);
    int tid = threadIdx.x;

    const float* src = x + ((size_t)(b*CIN + cc*64) * HH + h) * WW;
    for (int tt = tid; tt < 64*28; tt += 256) {
        int c = tt / 28, v = tt % 28;
        float4 f = *reinterpret_cast<const float4*>(src + (size_t)c*HH*WW + v*4);
        float* d = &tile[c*XPAD + v*4];
        d[0]=f.x; d[1]=f.y; d[2]=f.z; d[3]=f.w;
    }
    __syncthreads();

    if (tid < 224) {
        int w = tid >> 1, half = tid & 1;
        ushort o[32];
#pragma unroll
        for (int j = 0; j < 32; ++j) {
            __hip_bfloat16 v = __float2bfloat16(tile[(half*32 + j)*XPAD + w]);
            o[j] = *reinterpret_cast<ushort*>(&v);
        }
        ushort* dst = xb + (((size_t)(b*HH + h)*WW + w)*CIN + cc*64 + half*32);
        const uint4* o4 = reinterpret_cast<const uint4*>(o);
        uint4* d4 = reinterpret_cast<uint4*>(dst);
        d4[0]=o4[0]; d4[1]=o4[1]; d4[2]=o4[2]; d4[3]=o4[3];
    }
}

// ---- stage one 3-tap weight group (swizzled source) ----
__device__ inline void stage_w3(const ushort* __restrict__ wb, ushort* dstbuf,
                                int g, int tap_base, int cin, int wave, int lane) {
    int co = wave*16 + (lane >> 2);
    int ts = (lane & 3) ^ ((lane >> 3) & 3);
#pragma unroll
    for (int i = 0; i < 3; ++i) {
        const ushort* src = wb + (((size_t)(g*9 + tap_base + i)*COG + co)*CG + cin + ts*8);
        load_lds16(src, dstbuf + (i*COG + wave*16)*CK);
    }
}

// ---- one x-prefetch task: 16-px strip of one halo row (swizzled source) ----
__device__ inline void xpre_task(const ushort* __restrict__ xb, ushort* dstbuf,
                                 const ushort* __restrict__ zbuf,
                                 int b, int g, int oh0n, int cin, int t, int lane) {
    int rr = t / 7, ii = t % 7;
    int h  = oh0n - 1 + rr;
    int qv = lane >> 2;
    int w_in = ii*16 + qv;
    int ts = (lane & 3) ^ (((2*rr + 1 + qv) >> 1) & 3);
    const ushort* src = (h >= 0 && h < HH)
        ? xb + (((size_t)(b*HH + h)*WW + w_in)*CIN + g*CG + cin + ts*8)
        : zbuf + lane*8;
    load_lds16(src, dstbuf + (rr*114 + 1 + ii*16)*CK);
}

// one MFMA phase: kh=KH, kw=KW; 9 ds_read_b128 + 14 MFMA per wave
#define PHASE(KH, KW, XCUR, WBUF)                                           \
  {                                                                         \
    int sB = lk ^ (((2*(wr + (KH)) + l15 + (KW)) >> 1) & 3);                \
    const ushort* bbase = (XCUR) + ((wr + (KH))*114 + l15 + (KW))*CK + sB*8;\
    bf16x8 bfr[7];                                                          \
    _Pragma("unroll")                                                       \
    for (int n = 0; n < 7; ++n)                                             \
      bfr[n] = *reinterpret_cast<const bf16x8*>(bbase + n*16*CK);           \
    const ushort* abase = (WBUF) + ((KW)*COG + wm*32 + l15)*CK + sA*8;      \
    __builtin_amdgcn_s_setprio(1);                                          \
    _Pragma("unroll")                                                       \
    for (int m = 0; m < 2; ++m) {                                           \
      bf16x8 afr = *reinterpret_cast<const bf16x8*>(abase + m*16*CK);       \
      _Pragma("unroll")                                                     \
      for (int n = 0; n < 7; ++n)                                           \
        acc[m][n] = __builtin_amdgcn_mfma_f32_16x16x32_bf16(                \
            afr, bfr[n], acc[m][n], 0, 0, 0);                               \
    }                                                                       \
    __builtin_amdgcn_s_setprio(0);                                          \
  }

#define GROUP3(KH, XCUR, WBUF)   \
    PHASE(KH, 0, XCUR, WBUF)     \
    PHASE(KH, 1, XCUR, WBUF)     \
    PHASE(KH, 2, XCUR, WBUF)

// ---- main kernel: persistent implicit-GEMM grouped conv ----
// 256 blocks (1/CU, zero tail), 512 threads. Each block owns (g,b) and 7
// consecutive q-tiles of 2 output rows (q = qblk*7+e). Pipeline: wsb dbuf in
// 3-tap groups, xs dbuf per cin-chunk; every stage is issued one full group
// (~3 phases of MFMA) before the barrier that publishes it, so the vmcnt
// drain at each __syncthreads is ~free. Swizzle scheme identical to r2/r3
// (verified: bank conflicts == 0, absmax pass).
__global__ __launch_bounds__(512, 2) void k_conv(const ushort* __restrict__ xb,
                                                 const ushort* __restrict__ wb,
                                                 const float* __restrict__ bias,
                                                 float* __restrict__ out,
                                                 const ushort* __restrict__ zbuf) {
    __shared__ __align__(16) ushort xs[2][4*114*CK];     // 2 x 29184 B
    __shared__ __align__(16) ushort wsb[2][3*COG*CK];    // 2 x 24576 B (total 107520)

    int g    = blockIdx.x >> 7;          // 256 = 2g * 16b * 8qblk
    int rem  = blockIdx.x & 127;
    int b    = rem >> 3;
    int q0   = (rem & 7) * 7;

    int tid  = threadIdx.x;
    int wave = tid >> 6;
    int lane = tid & 63;
    int wm   = wave >> 1;          // cout quarter (0..3), 32 couts each
    int wr   = wave & 1;           // output row within pair (0..1)
    int l15  = lane & 15;
    int lk   = lane >> 4;
    int sA   = lk ^ ((l15 >> 1) & 3);    // weight-read slot (row-parity const)

    // zero pad columns (w=0,113) of both x buffers: 2*4*2*32 = 512 slots
    {
        int buf = tid >> 8, r2 = (tid >> 6) & 3, wc = (tid >> 5) & 1, ch = tid & 31;
        xs[buf][(r2*114 + wc*113)*CK + ch] = 0;
    }

    // bias registers (co is block/lane-constant all kernel)
    float breg[2][4];
#pragma unroll
    for (int m = 0; m < 2; ++m)
#pragma unroll
        for (int j = 0; j < 4; ++j)
            breg[m][j] = bias[g*COG + wm*32 + m*16 + lk*4 + j];

    f32x4 acc[2][7];
#pragma unroll
    for (int m = 0; m < 2; ++m)
#pragma unroll
        for (int n = 0; n < 7; ++n) acc[m][n] = f32x4{0.f,0.f,0.f,0.f};

    // prologue: x chunk CC=0 + w group (0,0)
    for (int t = wave; t < 28; t += 8)
        xpre_task(xb, xs[0], zbuf, b, g, 2*q0, 0, t, lane);
    stage_w3(wb, wsb[0], g, 0, 0, wave, lane);
    __syncthreads();

    // CC = global chunk counter: item e = CC>>2, cin-chunk = CC&3
#pragma unroll 1
    for (int CC = 0; CC < 28; ++CC) {
        int e    = CC >> 2;
        int oh0  = 2*(q0 + e);
        int p0   = CC & 1;
        const ushort* xcur = xs[p0];
        int cin  = (CC & 3) * CK;
        int cinN = ((CC + 1) & 3) * CK;
        int oh0n = 2*(q0 + ((CC + 1) >> 2));   // next-chunk rows (item-crossing ok)

        // ---- group kg=0 (kh=0): stage group(CC,1); x-prefetch tasks 0,1
        stage_w3(wb, wsb[p0^1], g, 3, cin, wave, lane);
        if (CC < 27) {
            xpre_task(xb, xs[p0^1], zbuf, b, g, oh0n, cinN, wave,     lane);
            xpre_task(xb, xs[p0^1], zbuf, b, g, oh0n, cinN, wave + 8, lane);
        }
        GROUP3(0, xcur, wsb[p0])
        __syncthreads();

        // ---- group kg=1 (kh=1): stage group(CC,2); x-prefetch tasks 2,3
        stage_w3(wb, wsb[p0], g, 6, cin, wave, lane);
        if (CC < 27) {
            xpre_task(xb, xs[p0^1], zbuf, b, g, oh0n, cinN, wave + 16, lane);
            if (wave + 24 < 28)
                xpre_task(xb, xs[p0^1], zbuf, b, g, oh0n, cinN, wave + 24, lane);
        }
        GROUP3(1, xcur, wsb[p0^1])
        __syncthreads();

        // ---- group kg=2 (kh=2): stage group(CC+1,0)
        if (CC < 27)
            stage_w3(wb, wsb[p0^1], g, 0, cinN, wave, lane);
        GROUP3(2, xcur, wsb[p0])
        __syncthreads();

        // ---- end of item: epilogue (overlaps next item's pipeline naturally)
        if ((CC & 3) == 3) {
            int oh = oh0 + wr;
#pragma unroll
            for (int m = 0; m < 2; ++m) {
                int co = g*COG + wm*32 + m*16 + lk*4;
#pragma unroll
                for (int j = 0; j < 4; ++j) {
                    float bv = breg[m][j];
                    float* orow = out + (((size_t)(b*CIN + co + j)*HH + oh)*WW);
#pragma unroll
                    for (int n = 0; n < 7; ++n)
                        orow[n*16 + l15] = acc[m][n][j] + bv;
                }
            }
#pragma unroll
            for (int m = 0; m < 2; ++m)
#pragma unroll
                for (int n = 0; n < 7; ++n) acc[m][n] = f32x4{0.f,0.f,0.f,0.f};
        }
    }
}

// ---- fallback: direct fp32 conv (used only if ws is too small) ----
__global__ __launch_bounds__(128) void k_direct(const float* __restrict__ x,
                                                const float* __restrict__ w,
                                                const float* __restrict__ bias,
                                                float* __restrict__ out) {
    int bid = blockIdx.x;          // B*Cout*H
    int oh  = bid % HH;
    int t   = bid / HH;
    int co  = t % CIN;
    int b   = t / CIN;
    int ow  = threadIdx.x;
    if (ow >= WW) return;
    int g = co / COG;
    float s = bias[co];
    const float* wp = w + (size_t)co*CG*9;
    const float* xp = x + ((size_t)b*CIN + g*CG)*HH*WW;
    for (int ci = 0; ci < CG; ++ci) {
        const float* xr = xp + (size_t)ci*HH*WW;
        const float* wr_ = wp + ci*9;
#pragma unroll
        for (int kh = 0; kh < 3; ++kh) {
            int ih = oh + kh - 1;
            if (ih < 0 || ih >= HH) continue;
#pragma unroll
            for (int kw = 0; kw < 3; ++kw) {
                int iw = ow + kw - 1;
                if (iw < 0 || iw >= WW) continue;
                s += xr[ih*WW + iw] * wr_[kh*3 + kw];
            }
        }
    }
    out[(((size_t)b*CIN + co)*HH + oh)*WW + ow] = s;
}

extern "C" void kernel_launch(void* const* d_in, const int* in_sizes, int n_in,
                              void* d_out, int out_size, void* d_ws, size_t ws_size,
                              hipStream_t stream) {
    const float* x    = (const float*)d_in[0];
    const float* w    = (const float*)d_in[1];
    const float* bias = (const float*)d_in[2];
    float* out        = (float*)d_out;

    if (ws_size >= WS_NEED) {
        ushort* wb   = (ushort*)d_ws;
        ushort* zb   = (ushort*)((char*)d_ws + ZBUF_OFF);
        ushort* xbuf = (ushort*)((char*)d_ws + XB_OFF);
        hipMemsetAsync(zb, 0, ZBUF_BYTES, stream);
        k_wcvt<<<1152, 256, 0, stream>>>(w, wb);
        k_xcvt<<<BATCH*HH*4, 256, 0, stream>>>(x, xbuf);
        k_conv<<<256, 512, 0, stream>>>(xbuf, wb, bias, out, zb);
    } else {
        k_direct<<<BATCH*CIN*HH, 128, 0, stream>>>(x, w, bias, out);
    }
}